// Round 7
// baseline (519.449 us; speedup 1.0000x reference)
//
#include <hip/hip_runtime.h>
#include <hip/hip_bf16.h>

typedef __hip_bfloat16 bf16;
typedef __attribute__((ext_vector_type(8))) __bf16 bf16x8;
typedef __attribute__((ext_vector_type(4))) float f32x4;

__device__ __forceinline__ f32x4 mfma16(bf16x8 a, bf16x8 b, f32x4 c) {
  return __builtin_amdgcn_mfma_f32_16x16x32_bf16(a, b, c, 0, 0, 0);
}

__device__ __forceinline__ void gload_lds16(const void* g, void* lds) {
  __builtin_amdgcn_global_load_lds(
      (const __attribute__((address_space(1))) unsigned int*)g,
      (__attribute__((address_space(3))) unsigned int*)lds, 16, 0, 0);
}

// ---------------------------------------------------------------------------
// fp32 -> bf16 converters
// ---------------------------------------------------------------------------
__global__ __launch_bounds__(256)
void cvt_x_k(const float* __restrict__ s, bf16* __restrict__ d)
{
  const int i = (blockIdx.x * 256 + threadIdx.x) * 8;
  float4 a = *(const float4*)(s + i);
  float4 b = *(const float4*)(s + i + 4);
  union { bf16 h[8]; bf16x8 v; } u;
  u.h[0] = __float2bfloat16(a.x); u.h[1] = __float2bfloat16(a.y);
  u.h[2] = __float2bfloat16(a.z); u.h[3] = __float2bfloat16(a.w);
  u.h[4] = __float2bfloat16(b.x); u.h[5] = __float2bfloat16(b.y);
  u.h[6] = __float2bfloat16(b.z); u.h[7] = __float2bfloat16(b.w);
  *(bf16x8*)(d + i) = u.v;
}

__global__ __launch_bounds__(256)
void cvt_w_k(const float* s0, const float* s1, const float* s2, const float* s3,
             const float* s4, const float* s5, const float* s6, bf16* __restrict__ d)
{
  const int mat = blockIdx.x >> 7, blk = blockIdx.x & 127;
  const float* s;
  switch (mat) {
    case 0: s = s0; break; case 1: s = s1; break; case 2: s = s2; break;
    case 3: s = s3; break; case 4: s = s4; break; case 5: s = s5; break;
    default: s = s6; break;
  }
  const int i = (blk * 256 + threadIdx.x) * 8;
  float4 a = *(const float4*)(s + i);
  float4 b = *(const float4*)(s + i + 4);
  union { bf16 h[8]; bf16x8 v; } u;
  u.h[0] = __float2bfloat16(a.x); u.h[1] = __float2bfloat16(a.y);
  u.h[2] = __float2bfloat16(a.z); u.h[3] = __float2bfloat16(a.w);
  u.h[4] = __float2bfloat16(b.x); u.h[5] = __float2bfloat16(b.y);
  u.h[6] = __float2bfloat16(b.z); u.h[7] = __float2bfloat16(b.w);
  *(bf16x8*)(d + mat * 262144 + i) = u.v;
}

// ---------------------------------------------------------------------------
// 256x256x(K=512) GEMM, 8 waves (2M x 4N), BK=64, 4 quadrant-phases per
// K-tile.  Counted vmcnt(4) placed BEFORE each phase barrier (wait-own ->
// barrier-publish: collective guarantee); never 0 in the loop.  Half-tile
// staging, T5 setprio, T1 XCD swizzle, XOR-swizzled LDS (both-sides).
// MODE 0: fp32 direct store.  MODE 1/2: bf16 QKV store [a][h][seq][e] via
// LDS-staged coalesced epilogue (m-decode per stage).
// ---------------------------------------------------------------------------
template<int MODE, int NBN>
__global__ __launch_bounds__(512)
void gemm2_k(const bf16* __restrict__ A,
             const bf16* __restrict__ W0, const bf16* __restrict__ W1, const bf16* __restrict__ W2,
             const float* __restrict__ Bi0, const float* __restrict__ Bi1, const float* __restrict__ Bi2,
             bf16* __restrict__ O0, bf16* __restrict__ O1, bf16* __restrict__ O2,
             float* __restrict__ F0)
{
  // 2 K-tile buffers x { A halves @0/16384, B halves @32768/49152 } = 128 KB
  __shared__ __align__(16) char smem[131072];

  const int tid  = threadIdx.x;
  const int lane = tid & 63;
  const int wid  = tid >> 6;        // 0..7
  const int wm   = wid >> 2;        // 0..1
  const int wn   = wid & 3;         // 0..3
  const int lq   = lane & 15, qd = lane >> 4;

  // T1: XCD-contiguous stripes (grid % 8 == 0)
  const int per = gridDim.x >> 3;
  const int logical = (blockIdx.x & 7) * per + (blockIdx.x >> 3);
  const int bm = logical / NBN;
  const int bn = logical % NBN;
  const int m0 = bm * 256;
  const int n0 = bn * 256;

  const bf16* Wb; const float* Bsel; int nbase;
  if (MODE == 0) { Wb = W0; Bsel = Bi0; nbase = n0; }
  else {
    const int mat = n0 >> 9; nbase = n0 & 511;
    Wb   = (mat == 0) ? W0 : ((mat == 1) ? W1 : W2);
    Bsel = (mat == 0) ? Bi0 : ((mat == 1) ? Bi1 : Bi2);
  }

  f32x4 acc[8][4];
#pragma unroll
  for (int i = 0; i < 8; ++i)
#pragma unroll
    for (int j = 0; j < 4; ++j) acc[i][j] = f32x4{0.f, 0.f, 0.f, 0.f};

  // stage one half-tile (X: 0=A tokens, 1=B weights; h: 0/1; K-tile ktt; buffer tb)
  auto stage_half = [&](int X, int h, int ktt, int tb) {
#pragma unroll
    for (int jj = 0; jj < 2; ++jj) {
      const int id = wid * 2 + jj;                  // 0..15
      const int r  = id * 8 + (lane >> 3);          // row in half 0..127
      const int cb = ktt * 128 + (((lane & 7) ^ (r & 7)) << 4);  // pre-swizzled
      const char* g = X ? (const char*)Wb + (size_t)(nbase + h * 128 + r) * 1024 + cb
                        : (const char*)A  + (size_t)(m0   + h * 128 + r) * 1024 + cb;
      gload_lds16(g, smem + tb * 65536 + X * 32768 + h * 16384 + id * 1024);
    }
  };

#define GPHASE(QM, QN, SX, SH, KOFF) do {                                         \
    const char* Ah = smem + bb + (QM) * 16384;                                    \
    const char* Bh = smem + bb + 32768 + (QN) * 16384;                            \
    bf16x8 af[4][2], bv[2][2];                                                    \
    _Pragma("unroll") for (int i = 0; i < 4; ++i) {                               \
      const int row = wm * 64 + i * 16 + lq;                                      \
      _Pragma("unroll") for (int kk = 0; kk < 2; ++kk)                            \
        af[i][kk] = *(const bf16x8*)(Ah + row * 128 + (((kk * 4 + qd) ^ (row & 7)) << 4)); \
    }                                                                             \
    _Pragma("unroll") for (int j = 0; j < 2; ++j) {                               \
      const int row = wn * 32 + j * 16 + lq;                                      \
      _Pragma("unroll") for (int kk = 0; kk < 2; ++kk)                            \
        bv[j][kk] = *(const bf16x8*)(Bh + row * 128 + (((kk * 4 + qd) ^ (row & 7)) << 4)); \
    }                                                                             \
    stage_half((SX), (SH), (kt + (KOFF)) & 7, (kt + (KOFF)) & 1);                 \
    __builtin_amdgcn_s_setprio(1);                                                \
    _Pragma("unroll") for (int kk = 0; kk < 2; ++kk)                              \
      _Pragma("unroll") for (int i = 0; i < 4; ++i)                               \
        _Pragma("unroll") for (int j = 0; j < 2; ++j)                             \
          acc[(QM) * 4 + i][(QN) * 2 + j] =                                       \
              mfma16(af[i][kk], bv[j][kk], acc[(QM) * 4 + i][(QN) * 2 + j]);      \
    __builtin_amdgcn_s_setprio(0);                                                \
    asm volatile("s_waitcnt vmcnt(4)" ::: "memory");  /* wait-own BEFORE barrier */\
    __builtin_amdgcn_s_barrier();                     /* publish to all waves   */\
    __builtin_amdgcn_sched_barrier(0);                /* no hoist past barrier  */\
  } while (0)

  // prologue: kt0 complete (A0,B0,B1,A1) + kt1's (A0,B1); confirm kt0, publish
  stage_half(0, 0, 0, 0); stage_half(1, 0, 0, 0);
  stage_half(1, 1, 0, 0); stage_half(0, 1, 0, 0);
  stage_half(0, 0, 1, 1); stage_half(1, 1, 1, 1);
  asm volatile("s_waitcnt vmcnt(4)" ::: "memory");
  __builtin_amdgcn_s_barrier();
  __builtin_amdgcn_sched_barrier(0);

  for (int kt = 0; kt < 8; ++kt) {     // K = 512, BK = 64
    const int bb = (kt & 1) * 65536;
    GPHASE(0, 0, 0, 1, 1);   // TL (A0·B0); stage A1 of kt+1
    GPHASE(0, 1, 1, 0, 1);   // TR (A0·B1); stage B0 of kt+1
    GPHASE(1, 1, 0, 0, 2);   // BR (A1·B1); stage A0 of kt+2
    GPHASE(1, 0, 1, 1, 2);   // BL (A1·B0); stage B1 of kt+2
  }
#undef GPHASE

  // drain all outstanding stage writes before reusing LDS / exiting
  asm volatile("s_waitcnt vmcnt(0)" ::: "memory");
  __builtin_amdgcn_s_barrier();
  __builtin_amdgcn_sched_barrier(0);

  float biasv[4];
#pragma unroll
  for (int ni = 0; ni < 4; ++ni) {
    const int col = (ni >> 1) * 128 + wn * 32 + (ni & 1) * 16 + lq;
    biasv[ni] = Bsel[(MODE == 0) ? (n0 + col) : (nbase + col)];
  }

  if (MODE == 0) {
#pragma unroll
    for (int mi = 0; mi < 8; ++mi)
#pragma unroll
      for (int r = 0; r < 4; ++r) {
        const int m = m0 + (mi >> 2) * 128 + wm * 64 + (mi & 3) * 16 + qd * 4 + r;
#pragma unroll
        for (int ni = 0; ni < 4; ++ni) {
          const int n = n0 + (ni >> 1) * 128 + wn * 32 + (ni & 1) * 16 + lq;
          F0[(size_t)m * 512 + n] = acc[mi][ni][r] + biasv[ni];
        }
      }
  } else {
    // two passes (qm = m-half); Ct logical [128][256] bf16, slot-swizzled
    const int mat = n0 >> 9;
    bf16* const Om = (mat == 0) ? O0 : ((mat == 1) ? O1 : O2);
    const int h0 = (n0 & 511) >> 6;          // first head of this 256-col chunk
#pragma unroll
    for (int qm = 0; qm < 2; ++qm) {
#pragma unroll
      for (int i = 0; i < 4; ++i)
#pragma unroll
        for (int r = 0; r < 4; ++r) {
          const int row = wm * 64 + i * 16 + qd * 4 + r;         // 0..127
          const int sw  = (row & 7) ^ (((row >> 3) & 3) << 3);
#pragma unroll
          for (int ni = 0; ni < 4; ++ni) {
            const int col  = (ni >> 1) * 128 + wn * 32 + (ni & 1) * 16 + lq;
            const int byte = row * 512 + (((col >> 3) ^ sw) << 4) + (col & 7) * 2;
            *(bf16*)(smem + byte) = __float2bfloat16(acc[qm * 4 + i][ni][r] + biasv[ni]);
          }
        }
      __syncthreads();
      {
        const int hh   = tid >> 7;           // 0..3
        const int mrow = tid & 127;
        const int m    = m0 + qm * 128 + mrow;
        int a, seq;
        if (MODE == 1) {
          const int b = m >> 13, c = (m >> 3) & 1023, pp = m & 7;
          a = (b * 32 + (c >> 5)) * 8 + pp;  seq = c & 31;
        } else {
          a = m >> 5;  seq = m & 31;
        }
        const int sw = (mrow & 7) ^ (((mrow >> 3) & 3) << 3);
        bf16* const dst = Om + ((size_t)((a * 8 + h0 + hh) * 32 + seq)) * 64;
#pragma unroll
        for (int j = 0; j < 8; ++j) {
          const bf16x8 v = *(const bf16x8*)(smem + mrow * 512 + (((hh * 8 + j) ^ sw) << 4));
          *(bf16x8*)(dst + j * 8) = v;
        }
      }
      __syncthreads();
    }
  }
}

// ---------------------------------------------------------------------------
// Attention: one wave = one (a,h) task. L=32, E=64. (proven round-5 kernel)
// ---------------------------------------------------------------------------
template<int STAGE>
__global__ __launch_bounds__(256)
void attn_k(const bf16* __restrict__ Q, const bf16* __restrict__ K,
            const bf16* __restrict__ V, bf16* __restrict__ Y)
{
  __shared__ __align__(16) char Plds[4][32 * 80];
  __shared__ __align__(16) char Vlds[4][32 * 132];
  const int tid  = threadIdx.x;
  const int lane = tid & 63;
  const int w    = tid >> 6;
  const int task = blockIdx.x * 4 + w;
  const int a = task >> 3, h = task & 7;
  const int lq = lane & 15, qd = lane >> 4;

  const bf16* Qb = Q + (size_t)(a * 8 + h) * 2048;
  const bf16* Kb = K + (size_t)(a * 8 + h) * 2048;
  const bf16* Vb = V + (size_t)(a * 8 + h) * 2048;

  {
    const int r  = lane >> 1;
    const int c0 = (lane & 1) * 32;
    union { bf16x8 v; unsigned u[4]; } t0, t1, t2, t3;
    t0.v = *(const bf16x8*)(Vb + r * 64 + c0);
    t1.v = *(const bf16x8*)(Vb + r * 64 + c0 + 8);
    t2.v = *(const bf16x8*)(Vb + r * 64 + c0 + 16);
    t3.v = *(const bf16x8*)(Vb + r * 64 + c0 + 24);
    unsigned* dst = (unsigned*)(Vlds[w] + r * 132 + c0 * 2);
#pragma unroll
    for (int j = 0; j < 4; ++j) dst[j]      = t0.u[j];
#pragma unroll
    for (int j = 0; j < 4; ++j) dst[4 + j]  = t1.u[j];
#pragma unroll
    for (int j = 0; j < 4; ++j) dst[8 + j]  = t2.u[j];
#pragma unroll
    for (int j = 0; j < 4; ++j) dst[12 + j] = t3.u[j];
  }

  bf16x8 qf[2][2], kf[2][2];
#pragma unroll
  for (int mi = 0; mi < 2; ++mi)
#pragma unroll
    for (int ks = 0; ks < 2; ++ks) {
      qf[mi][ks] = *(const bf16x8*)(Qb + (mi * 16 + lq) * 64 + ks * 32 + qd * 8);
      kf[mi][ks] = *(const bf16x8*)(Kb + (mi * 16 + lq) * 64 + ks * 32 + qd * 8);
    }

  f32x4 s[2][2];
#pragma unroll
  for (int mi = 0; mi < 2; ++mi)
#pragma unroll
    for (int ni = 0; ni < 2; ++ni) {
      s[mi][ni] = f32x4{0.f, 0.f, 0.f, 0.f};
#pragma unroll
      for (int ks = 0; ks < 2; ++ks)
        s[mi][ni] = mfma16(qf[mi][ks], kf[ni][ks], s[mi][ni]);
    }

  char* Pw = Plds[w];
  float rden[2][4];
#pragma unroll
  for (int mi = 0; mi < 2; ++mi) {
#pragma unroll
    for (int r = 0; r < 4; ++r) {
      float v0 = s[mi][0][r] * 0.125f, v1 = s[mi][1][r] * 0.125f;
      float mx = fmaxf(v0, v1);
#pragma unroll
      for (int d = 1; d < 16; d <<= 1) mx = fmaxf(mx, __shfl_xor(mx, d, 64));
      const float p0 = __expf(v0 - mx), p1 = __expf(v1 - mx);
      float sm = p0 + p1;
#pragma unroll
      for (int d = 1; d < 16; d <<= 1) sm += __shfl_xor(sm, d, 64);
      rden[mi][r] = 1.f / sm;
      const int qrow = mi * 16 + qd * 4 + r;
      bf16* prow = (bf16*)(Pw + qrow * 80);
      prow[lq]      = __float2bfloat16(p0);
      prow[16 + lq] = __float2bfloat16(p1);
    }
  }
  asm volatile("s_waitcnt lgkmcnt(0)" ::: "memory");
  __builtin_amdgcn_sched_barrier(0);

  bf16x8 pf[2];
#pragma unroll
  for (int mi = 0; mi < 2; ++mi)
    pf[mi] = *(const bf16x8*)(Pw + (mi * 16 + lq) * 80 + qd * 16);

  bf16x8 vf[4];
#pragma unroll
  for (int ni = 0; ni < 4; ++ni) {
    union { bf16 h[8]; bf16x8 v; } uv;
#pragma unroll
    for (int j = 0; j < 8; ++j)
      uv.h[j] = *(const bf16*)(Vlds[w] + (qd * 8 + j) * 132 + (ni * 16 + lq) * 2);
    vf[ni] = uv.v;
  }

  f32x4 o[2][4];
#pragma unroll
  for (int mi = 0; mi < 2; ++mi)
#pragma unroll
    for (int ni = 0; ni < 4; ++ni) {
      o[mi][ni] = f32x4{0.f, 0.f, 0.f, 0.f};
      o[mi][ni] = mfma16(pf[mi], vf[ni], o[mi][ni]);
    }

  int rowbase;
  if (STAGE == 1) { const int p = a & 7, ng = (a >> 3) & 31, b = a >> 8; rowbase = b * 8192 + p * 32 + ng; }
  else            { const int p = a & 7, i  = (a >> 3) & 31, b = a >> 8; rowbase = b * 8192 + i * 8 + p; }

#pragma unroll
  for (int mi = 0; mi < 2; ++mi) {
#pragma unroll
    for (int r = 0; r < 4; ++r) {
      const int q   = mi * 16 + qd * 4 + r;
      const int row = rowbase + q * 256;
      const float rd = rden[mi][r];
#pragma unroll
      for (int ni = 0; ni < 4; ++ni) {
        const int e = ni * 16 + lq;
        Y[(size_t)row * 512 + h * 64 + e] = __float2bfloat16(o[mi][ni][r] * rd);
      }
    }
  }
}

// ---------------------------------------------------------------------------
extern "C" void kernel_launch(void* const* d_in, const int* in_sizes, int n_in,
                              void* d_out, int out_size, void* d_ws, size_t ws_size,
                              hipStream_t stream) {
  const float* x   = (const float*)d_in[0];
  const float* q1w = (const float*)d_in[1];
  const float* q1b = (const float*)d_in[2];
  const float* k1w = (const float*)d_in[3];
  const float* k1b = (const float*)d_in[4];
  const float* v1w = (const float*)d_in[5];
  const float* v1b = (const float*)d_in[6];
  const float* q2w = (const float*)d_in[7];
  const float* q2b = (const float*)d_in[8];
  const float* k2w = (const float*)d_in[9];
  const float* k2b = (const float*)d_in[10];
  const float* v2w = (const float*)d_in[11];
  const float* v2b = (const float*)d_in[12];
  const float* ow  = (const float*)d_in[13];
  const float* ob  = (const float*)d_in[14];
  float* out = (float*)d_out;

  const size_t TOK = 65536ull * 512ull;
  const size_t WS1 = 262144;
  bf16* Xbf = (bf16*)d_ws;
  bf16* Qb  = Xbf + TOK;
  bf16* Kb  = Qb + TOK;
  bf16* Vb  = Kb + TOK;
  bf16* Wbf = Vb + TOK;   // 7 x 512x512 (q1,k1,v1,q2,k2,v2,ow)
  bf16* X2  = Xbf;

  cvt_x_k<<<16384, 256, 0, stream>>>(x, Xbf);
  cvt_w_k<<<7 * 128, 256, 0, stream>>>(q1w, k1w, v1w, q2w, k2w, v2w, ow, Wbf);

  gemm2_k<1, 6><<<1536, 512, 0, stream>>>(Xbf, Wbf, Wbf + WS1, Wbf + 2 * WS1,
                                          q1b, k1b, v1b, Qb, Kb, Vb, nullptr);
  attn_k<1><<<4096, 256, 0, stream>>>(Qb, Kb, Vb, X2);
  gemm2_k<2, 6><<<1536, 512, 0, stream>>>(X2, Wbf + 3 * WS1, Wbf + 4 * WS1, Wbf + 5 * WS1,
                                          q2b, k2b, v2b, Qb, Kb, Vb, nullptr);
  attn_k<2><<<4096, 256, 0, stream>>>(Qb, Kb, Vb, X2);
  gemm2_k<0, 2><<<512, 512, 0, stream>>>(X2, Wbf + 6 * WS1, Wbf + 6 * WS1, Wbf + 6 * WS1,
                                         ob, ob, ob, nullptr, nullptr, nullptr, out);
}

// Round 8
// 501.191 us; speedup vs baseline: 1.0364x; 1.0364x over previous
//
#include <hip/hip_runtime.h>
#include <hip/hip_bf16.h>

typedef __hip_bfloat16 bf16;
typedef __attribute__((ext_vector_type(8))) __bf16 bf16x8;
typedef __attribute__((ext_vector_type(4))) float f32x4;

__device__ __forceinline__ f32x4 mfma16(bf16x8 a, bf16x8 b, f32x4 c) {
  return __builtin_amdgcn_mfma_f32_16x16x32_bf16(a, b, c, 0, 0, 0);
}

__device__ __forceinline__ void gload_lds16(const void* g, void* lds) {
  __builtin_amdgcn_global_load_lds(
      (const __attribute__((address_space(1))) unsigned int*)g,
      (__attribute__((address_space(3))) unsigned int*)lds, 16, 0, 0);
}

// ---------------------------------------------------------------------------
// fp32 -> bf16 converters
// ---------------------------------------------------------------------------
__global__ __launch_bounds__(256)
void cvt_x_k(const float* __restrict__ s, bf16* __restrict__ d)
{
  const int i = (blockIdx.x * 256 + threadIdx.x) * 8;
  float4 a = *(const float4*)(s + i);
  float4 b = *(const float4*)(s + i + 4);
  union { bf16 h[8]; bf16x8 v; } u;
  u.h[0] = __float2bfloat16(a.x); u.h[1] = __float2bfloat16(a.y);
  u.h[2] = __float2bfloat16(a.z); u.h[3] = __float2bfloat16(a.w);
  u.h[4] = __float2bfloat16(b.x); u.h[5] = __float2bfloat16(b.y);
  u.h[6] = __float2bfloat16(b.z); u.h[7] = __float2bfloat16(b.w);
  *(bf16x8*)(d + i) = u.v;
}

__global__ __launch_bounds__(256)
void cvt_w_k(const float* s0, const float* s1, const float* s2, const float* s3,
             const float* s4, const float* s5, const float* s6, bf16* __restrict__ d)
{
  const int mat = blockIdx.x >> 7, blk = blockIdx.x & 127;
  const float* s;
  switch (mat) {
    case 0: s = s0; break; case 1: s = s1; break; case 2: s = s2; break;
    case 3: s = s3; break; case 4: s = s4; break; case 5: s = s5; break;
    default: s = s6; break;
  }
  const int i = (blk * 256 + threadIdx.x) * 8;
  float4 a = *(const float4*)(s + i);
  float4 b = *(const float4*)(s + i + 4);
  union { bf16 h[8]; bf16x8 v; } u;
  u.h[0] = __float2bfloat16(a.x); u.h[1] = __float2bfloat16(a.y);
  u.h[2] = __float2bfloat16(a.z); u.h[3] = __float2bfloat16(a.w);
  u.h[4] = __float2bfloat16(b.x); u.h[5] = __float2bfloat16(b.y);
  u.h[6] = __float2bfloat16(b.z); u.h[7] = __float2bfloat16(b.w);
  *(bf16x8*)(d + mat * 262144 + i) = u.v;
}

// ---------------------------------------------------------------------------
// 256x256x(K=512) GEMM, 8 waves (2M x 4N), BK=64, 4 quadrant-phases/K-tile
// with FRAGMENT REUSE across phases (each LDS fragment read once per K-tile):
//   P1: read A0,B0 -> TL   (stage A1 of kt+1)
//   P2: read B1    -> TR   (stage B0 of kt+1)    [reuse A0]
//   P3: read A1    -> BR   (stage A0 of kt+2)    [reuse B1]
//   P4: (no reads) -> BL   (stage B1 of kt+2)    [reuse A1,B0]
// Counted vmcnt(4) before each barrier (wait-own -> publish); never 0 in loop.
// T5 setprio, T1 XCD swizzle, XOR-swizzled LDS (both-sides).
// MODE 0: fp32 direct store.  MODE 1/2: bf16 QKV store [a][h][seq][e] via
// LDS-staged coalesced epilogue (m-decode per stage).
// ---------------------------------------------------------------------------
template<int MODE, int NBN>
__global__ __launch_bounds__(512)
void gemm2_k(const bf16* __restrict__ A,
             const bf16* __restrict__ W0, const bf16* __restrict__ W1, const bf16* __restrict__ W2,
             const float* __restrict__ Bi0, const float* __restrict__ Bi1, const float* __restrict__ Bi2,
             bf16* __restrict__ O0, bf16* __restrict__ O1, bf16* __restrict__ O2,
             float* __restrict__ F0)
{
  // 2 K-tile buffers x { A halves @0/16384, B halves @32768/49152 } = 128 KB
  __shared__ __align__(16) char smem[131072];

  const int tid  = threadIdx.x;
  const int lane = tid & 63;
  const int wid  = tid >> 6;        // 0..7
  const int wm   = wid >> 2;        // 0..1
  const int wn   = wid & 3;         // 0..3
  const int lq   = lane & 15, qd = lane >> 4;

  // T1: XCD-contiguous stripes (grid % 8 == 0)
  const int per = gridDim.x >> 3;
  const int logical = (blockIdx.x & 7) * per + (blockIdx.x >> 3);
  const int bm = logical / NBN;
  const int bn = logical % NBN;
  const int m0 = bm * 256;
  const int n0 = bn * 256;

  const bf16* Wb; const float* Bsel; int nbase;
  if (MODE == 0) { Wb = W0; Bsel = Bi0; nbase = n0; }
  else {
    const int mat = n0 >> 9; nbase = n0 & 511;
    Wb   = (mat == 0) ? W0 : ((mat == 1) ? W1 : W2);
    Bsel = (mat == 0) ? Bi0 : ((mat == 1) ? Bi1 : Bi2);
  }

  f32x4 acc[8][4];
#pragma unroll
  for (int i = 0; i < 8; ++i)
#pragma unroll
    for (int j = 0; j < 4; ++j) acc[i][j] = f32x4{0.f, 0.f, 0.f, 0.f};

  // stage one half-tile (X: 0=A tokens, 1=B weights; h: 0/1; K-tile ktt; buffer tb)
  auto stage_half = [&](int X, int h, int ktt, int tb) {
#pragma unroll
    for (int jj = 0; jj < 2; ++jj) {
      const int id = wid * 2 + jj;                  // 0..15
      const int r  = id * 8 + (lane >> 3);          // row in half 0..127
      const int cb = ktt * 128 + (((lane & 7) ^ (r & 7)) << 4);  // pre-swizzled
      const char* g = X ? (const char*)Wb + (size_t)(nbase + h * 128 + r) * 1024 + cb
                        : (const char*)A  + (size_t)(m0   + h * 128 + r) * 1024 + cb;
      gload_lds16(g, smem + tb * 65536 + X * 32768 + h * 16384 + id * 1024);
    }
  };

  auto lda = [&](bf16x8 (&af)[4][2], const char* Ah) {
#pragma unroll
    for (int i = 0; i < 4; ++i) {
      const int row = wm * 64 + i * 16 + lq;
#pragma unroll
      for (int kk = 0; kk < 2; ++kk)
        af[i][kk] = *(const bf16x8*)(Ah + row * 128 + (((kk * 4 + qd) ^ (row & 7)) << 4));
    }
  };
  auto ldb = [&](bf16x8 (&bv)[2][2], const char* Bh) {
#pragma unroll
    for (int j = 0; j < 2; ++j) {
      const int row = wn * 32 + j * 16 + lq;
#pragma unroll
      for (int kk = 0; kk < 2; ++kk)
        bv[j][kk] = *(const bf16x8*)(Bh + row * 128 + (((kk * 4 + qd) ^ (row & 7)) << 4));
    }
  };

#define FMA_Q(AF, BV, QM, QN) do {                                               \
    __builtin_amdgcn_s_setprio(1);                                              \
    _Pragma("unroll") for (int kk = 0; kk < 2; ++kk)                             \
      _Pragma("unroll") for (int i = 0; i < 4; ++i)                              \
        _Pragma("unroll") for (int j = 0; j < 2; ++j)                            \
          acc[(QM) * 4 + i][(QN) * 2 + j] =                                      \
              mfma16(AF[i][kk], BV[j][kk], acc[(QM) * 4 + i][(QN) * 2 + j]);     \
    __builtin_amdgcn_s_setprio(0);                                               \
  } while (0)

#define PHASE_END() do {                                                         \
    asm volatile("s_waitcnt vmcnt(4)" ::: "memory");                             \
    __builtin_amdgcn_s_barrier();                                                \
    __builtin_amdgcn_sched_barrier(0);                                           \
  } while (0)

  // prologue stages: A0(0),B0(0),B1(0),A1(0),A0(1),B1(1)
  stage_half(0, 0, 0, 0); stage_half(1, 0, 0, 0);
  stage_half(1, 1, 0, 0); stage_half(0, 1, 0, 0);
  stage_half(0, 0, 1, 1); stage_half(1, 1, 1, 1);
  PHASE_END();   // first 4 stages landed & published

  bf16x8 afA[4][2], afB[4][2], bv0[2][2], bv1[2][2];

  for (int kt = 0; kt < 8; ++kt) {     // K = 512, BK = 64
    const int bb = (kt & 1) * 65536;
    // P1: TL = A0 x B0 ; stage A1(kt+1)
    lda(afA, smem + bb);
    ldb(bv0, smem + bb + 32768);
    stage_half(0, 1, (kt + 1) & 7, (kt + 1) & 1);
    FMA_Q(afA, bv0, 0, 0);
    PHASE_END();
    // P2: TR = A0 x B1 ; stage B0(kt+1)
    ldb(bv1, smem + bb + 32768 + 16384);
    stage_half(1, 0, (kt + 1) & 7, (kt + 1) & 1);
    FMA_Q(afA, bv1, 0, 1);
    PHASE_END();
    // P3: BR = A1 x B1 ; stage A0(kt+2)
    lda(afB, smem + bb + 16384);
    stage_half(0, 0, (kt + 2) & 7, (kt + 2) & 1);
    FMA_Q(afB, bv1, 1, 1);
    PHASE_END();
    // P4: BL = A1 x B0 ; stage B1(kt+2)
    stage_half(1, 1, (kt + 2) & 7, (kt + 2) & 1);
    FMA_Q(afB, bv0, 1, 0);
    PHASE_END();
  }
#undef FMA_Q
#undef PHASE_END

  // drain all outstanding stage writes before reusing LDS / exiting
  asm volatile("s_waitcnt vmcnt(0)" ::: "memory");
  __builtin_amdgcn_s_barrier();
  __builtin_amdgcn_sched_barrier(0);

  float biasv[4];
#pragma unroll
  for (int ni = 0; ni < 4; ++ni) {
    const int col = (ni >> 1) * 128 + wn * 32 + (ni & 1) * 16 + lq;
    biasv[ni] = Bsel[(MODE == 0) ? (n0 + col) : (nbase + col)];
  }

  if (MODE == 0) {
#pragma unroll
    for (int mi = 0; mi < 8; ++mi)
#pragma unroll
      for (int r = 0; r < 4; ++r) {
        const int m = m0 + (mi >> 2) * 128 + wm * 64 + (mi & 3) * 16 + qd * 4 + r;
#pragma unroll
        for (int ni = 0; ni < 4; ++ni) {
          const int n = n0 + (ni >> 1) * 128 + wn * 32 + (ni & 1) * 16 + lq;
          F0[(size_t)m * 512 + n] = acc[mi][ni][r] + biasv[ni];
        }
      }
  } else {
    // two passes (qm = m-half); Ct logical [128][256] bf16, slot-swizzled
    const int mat = n0 >> 9;
    bf16* const Om = (mat == 0) ? O0 : ((mat == 1) ? O1 : O2);
    const int h0 = (n0 & 511) >> 6;          // first head of this 256-col chunk
#pragma unroll
    for (int qm = 0; qm < 2; ++qm) {
#pragma unroll
      for (int i = 0; i < 4; ++i)
#pragma unroll
        for (int r = 0; r < 4; ++r) {
          const int row = wm * 64 + i * 16 + qd * 4 + r;         // 0..127
          const int sw  = (row & 7) ^ (((row >> 3) & 3) << 3);
#pragma unroll
          for (int ni = 0; ni < 4; ++ni) {
            const int col  = (ni >> 1) * 128 + wn * 32 + (ni & 1) * 16 + lq;
            const int byte = row * 512 + (((col >> 3) ^ sw) << 4) + (col & 7) * 2;
            *(bf16*)(smem + byte) = __float2bfloat16(acc[qm * 4 + i][ni][r] + biasv[ni]);
          }
        }
      __syncthreads();
      {
        const int hh   = tid >> 7;           // 0..3
        const int mrow = tid & 127;
        const int m    = m0 + qm * 128 + mrow;
        int a, seq;
        if (MODE == 1) {
          const int b = m >> 13, c = (m >> 3) & 1023, pp = m & 7;
          a = (b * 32 + (c >> 5)) * 8 + pp;  seq = c & 31;
        } else {
          a = m >> 5;  seq = m & 31;
        }
        const int sw = (mrow & 7) ^ (((mrow >> 3) & 3) << 3);
        bf16* const dst = Om + ((size_t)((a * 8 + h0 + hh) * 32 + seq)) * 64;
#pragma unroll
        for (int j = 0; j < 8; ++j) {
          const bf16x8 v = *(const bf16x8*)(smem + mrow * 512 + (((hh * 8 + j) ^ sw) << 4));
          *(bf16x8*)(dst + j * 8) = v;
        }
      }
      __syncthreads();
    }
  }
}

// ---------------------------------------------------------------------------
// Attention: one wave = one (a,h) task. L=32, E=64. (proven round-5 kernel)
// ---------------------------------------------------------------------------
template<int STAGE>
__global__ __launch_bounds__(256)
void attn_k(const bf16* __restrict__ Q, const bf16* __restrict__ K,
            const bf16* __restrict__ V, bf16* __restrict__ Y)
{
  __shared__ __align__(16) char Plds[4][32 * 80];
  __shared__ __align__(16) char Vlds[4][32 * 132];
  const int tid  = threadIdx.x;
  const int lane = tid & 63;
  const int w    = tid >> 6;
  const int task = blockIdx.x * 4 + w;
  const int a = task >> 3, h = task & 7;
  const int lq = lane & 15, qd = lane >> 4;

  const bf16* Qb = Q + (size_t)(a * 8 + h) * 2048;
  const bf16* Kb = K + (size_t)(a * 8 + h) * 2048;
  const bf16* Vb = V + (size_t)(a * 8 + h) * 2048;

  {
    const int r  = lane >> 1;
    const int c0 = (lane & 1) * 32;
    union { bf16x8 v; unsigned u[4]; } t0, t1, t2, t3;
    t0.v = *(const bf16x8*)(Vb + r * 64 + c0);
    t1.v = *(const bf16x8*)(Vb + r * 64 + c0 + 8);
    t2.v = *(const bf16x8*)(Vb + r * 64 + c0 + 16);
    t3.v = *(const bf16x8*)(Vb + r * 64 + c0 + 24);
    unsigned* dst = (unsigned*)(Vlds[w] + r * 132 + c0 * 2);
#pragma unroll
    for (int j = 0; j < 4; ++j) dst[j]      = t0.u[j];
#pragma unroll
    for (int j = 0; j < 4; ++j) dst[4 + j]  = t1.u[j];
#pragma unroll
    for (int j = 0; j < 4; ++j) dst[8 + j]  = t2.u[j];
#pragma unroll
    for (int j = 0; j < 4; ++j) dst[12 + j] = t3.u[j];
  }

  bf16x8 qf[2][2], kf[2][2];
#pragma unroll
  for (int mi = 0; mi < 2; ++mi)
#pragma unroll
    for (int ks = 0; ks < 2; ++ks) {
      qf[mi][ks] = *(const bf16x8*)(Qb + (mi * 16 + lq) * 64 + ks * 32 + qd * 8);
      kf[mi][ks] = *(const bf16x8*)(Kb + (mi * 16 + lq) * 64 + ks * 32 + qd * 8);
    }

  f32x4 s[2][2];
#pragma unroll
  for (int mi = 0; mi < 2; ++mi)
#pragma unroll
    for (int ni = 0; ni < 2; ++ni) {
      s[mi][ni] = f32x4{0.f, 0.f, 0.f, 0.f};
#pragma unroll
      for (int ks = 0; ks < 2; ++ks)
        s[mi][ni] = mfma16(qf[mi][ks], kf[ni][ks], s[mi][ni]);
    }

  char* Pw = Plds[w];
  float rden[2][4];
#pragma unroll
  for (int mi = 0; mi < 2; ++mi) {
#pragma unroll
    for (int r = 0; r < 4; ++r) {
      float v0 = s[mi][0][r] * 0.125f, v1 = s[mi][1][r] * 0.125f;
      float mx = fmaxf(v0, v1);
#pragma unroll
      for (int d = 1; d < 16; d <<= 1) mx = fmaxf(mx, __shfl_xor(mx, d, 64));
      const float p0 = __expf(v0 - mx), p1 = __expf(v1 - mx);
      float sm = p0 + p1;
#pragma unroll
      for (int d = 1; d < 16; d <<= 1) sm += __shfl_xor(sm, d, 64);
      rden[mi][r] = 1.f / sm;
      const int qrow = mi * 16 + qd * 4 + r;
      bf16* prow = (bf16*)(Pw + qrow * 80);
      prow[lq]      = __float2bfloat16(p0);
      prow[16 + lq] = __float2bfloat16(p1);
    }
  }
  asm volatile("s_waitcnt lgkmcnt(0)" ::: "memory");
  __builtin_amdgcn_sched_barrier(0);

  bf16x8 pf[2];
#pragma unroll
  for (int mi = 0; mi < 2; ++mi)
    pf[mi] = *(const bf16x8*)(Pw + (mi * 16 + lq) * 80 + qd * 16);

  bf16x8 vf[4];
#pragma unroll
  for (int ni = 0; ni < 4; ++ni) {
    union { bf16 h[8]; bf16x8 v; } uv;
#pragma unroll
    for (int j = 0; j < 8; ++j)
      uv.h[j] = *(const bf16*)(Vlds[w] + (qd * 8 + j) * 132 + (ni * 16 + lq) * 2);
    vf[ni] = uv.v;
  }

  f32x4 o[2][4];
#pragma unroll
  for (int mi = 0; mi < 2; ++mi)
#pragma unroll
    for (int ni = 0; ni < 4; ++ni) {
      o[mi][ni] = f32x4{0.f, 0.f, 0.f, 0.f};
      o[mi][ni] = mfma16(pf[mi], vf[ni], o[mi][ni]);
    }

  int rowbase;
  if (STAGE == 1) { const int p = a & 7, ng = (a >> 3) & 31, b = a >> 8; rowbase = b * 8192 + p * 32 + ng; }
  else            { const int p = a & 7, i  = (a >> 3) & 31, b = a >> 8; rowbase = b * 8192 + i * 8 + p; }

#pragma unroll
  for (int mi = 0; mi < 2; ++mi) {
#pragma unroll
    for (int r = 0; r < 4; ++r) {
      const int q   = mi * 16 + qd * 4 + r;
      const int row = rowbase + q * 256;
      const float rd = rden[mi][r];
#pragma unroll
      for (int ni = 0; ni < 4; ++ni) {
        const int e = ni * 16 + lq;
        Y[(size_t)row * 512 + h * 64 + e] = __float2bfloat16(o[mi][ni][r] * rd);
      }
    }
  }
}

// ---------------------------------------------------------------------------
extern "C" void kernel_launch(void* const* d_in, const int* in_sizes, int n_in,
                              void* d_out, int out_size, void* d_ws, size_t ws_size,
                              hipStream_t stream) {
  const float* x   = (const float*)d_in[0];
  const float* q1w = (const float*)d_in[1];
  const float* q1b = (const float*)d_in[2];
  const float* k1w = (const float*)d_in[3];
  const float* k1b = (const float*)d_in[4];
  const float* v1w = (const float*)d_in[5];
  const float* v1b = (const float*)d_in[6];
  const float* q2w = (const float*)d_in[7];
  const float* q2b = (const float*)d_in[8];
  const float* k2w = (const float*)d_in[9];
  const float* k2b = (const float*)d_in[10];
  const float* v2w = (const float*)d_in[11];
  const float* v2b = (const float*)d_in[12];
  const float* ow  = (const float*)d_in[13];
  const float* ob  = (const float*)d_in[14];
  float* out = (float*)d_out;

  const size_t TOK = 65536ull * 512ull;
  const size_t WS1 = 262144;
  bf16* Xbf = (bf16*)d_ws;
  bf16* Qb  = Xbf + TOK;
  bf16* Kb  = Qb + TOK;
  bf16* Vb  = Kb + TOK;
  bf16* Wbf = Vb + TOK;   // 7 x 512x512 (q1,k1,v1,q2,k2,v2,ow)
  bf16* X2  = Xbf;

  cvt_x_k<<<16384, 256, 0, stream>>>(x, Xbf);
  cvt_w_k<<<7 * 128, 256, 0, stream>>>(q1w, k1w, v1w, q2w, k2w, v2w, ow, Wbf);

  gemm2_k<1, 6><<<1536, 512, 0, stream>>>(Xbf, Wbf, Wbf + WS1, Wbf + 2 * WS1,
                                          q1b, k1b, v1b, Qb, Kb, Vb, nullptr);
  attn_k<1><<<4096, 256, 0, stream>>>(Qb, Kb, Vb, X2);
  gemm2_k<2, 6><<<1536, 512, 0, stream>>>(X2, Wbf + 3 * WS1, Wbf + 4 * WS1, Wbf + 5 * WS1,
                                          q2b, k2b, v2b, Qb, Kb, Vb, nullptr);
  attn_k<2><<<4096, 256, 0, stream>>>(Qb, Kb, Vb, X2);
  gemm2_k<0, 2><<<512, 512, 0, stream>>>(X2, Wbf + 6 * WS1, Wbf + 6 * WS1, Wbf + 6 * WS1,
                                         ob, ob, ob, nullptr, nullptr, nullptr, out);
}

// Round 9
// 499.414 us; speedup vs baseline: 1.0401x; 1.0036x over previous
//
#include <hip/hip_runtime.h>
#include <hip/hip_bf16.h>

typedef __hip_bfloat16 bf16;
typedef __attribute__((ext_vector_type(8))) __bf16 bf16x8;
typedef __attribute__((ext_vector_type(4))) float f32x4;

__device__ __forceinline__ f32x4 mfma16(bf16x8 a, bf16x8 b, f32x4 c) {
  return __builtin_amdgcn_mfma_f32_16x16x32_bf16(a, b, c, 0, 0, 0);
}

__device__ __forceinline__ void gload_lds16(const void* g, void* lds) {
  __builtin_amdgcn_global_load_lds(
      (const __attribute__((address_space(1))) unsigned int*)g,
      (__attribute__((address_space(3))) unsigned int*)lds, 16, 0, 0);
}

// ---------------------------------------------------------------------------
// fp32 -> bf16 converters
// ---------------------------------------------------------------------------
__global__ __launch_bounds__(256)
void cvt_x_k(const float* __restrict__ s, bf16* __restrict__ d)
{
  const int i = (blockIdx.x * 256 + threadIdx.x) * 8;
  float4 a = *(const float4*)(s + i);
  float4 b = *(const float4*)(s + i + 4);
  union { bf16 h[8]; bf16x8 v; } u;
  u.h[0] = __float2bfloat16(a.x); u.h[1] = __float2bfloat16(a.y);
  u.h[2] = __float2bfloat16(a.z); u.h[3] = __float2bfloat16(a.w);
  u.h[4] = __float2bfloat16(b.x); u.h[5] = __float2bfloat16(b.y);
  u.h[6] = __float2bfloat16(b.z); u.h[7] = __float2bfloat16(b.w);
  *(bf16x8*)(d + i) = u.v;
}

__global__ __launch_bounds__(256)
void cvt_w_k(const float* s0, const float* s1, const float* s2, const float* s3,
             const float* s4, const float* s5, const float* s6, bf16* __restrict__ d)
{
  const int mat = blockIdx.x >> 7, blk = blockIdx.x & 127;
  const float* s;
  switch (mat) {
    case 0: s = s0; break; case 1: s = s1; break; case 2: s = s2; break;
    case 3: s = s3; break; case 4: s = s4; break; case 5: s = s5; break;
    default: s = s6; break;
  }
  const int i = (blk * 256 + threadIdx.x) * 8;
  float4 a = *(const float4*)(s + i);
  float4 b = *(const float4*)(s + i + 4);
  union { bf16 h[8]; bf16x8 v; } u;
  u.h[0] = __float2bfloat16(a.x); u.h[1] = __float2bfloat16(a.y);
  u.h[2] = __float2bfloat16(a.z); u.h[3] = __float2bfloat16(a.w);
  u.h[4] = __float2bfloat16(b.x); u.h[5] = __float2bfloat16(b.y);
  u.h[6] = __float2bfloat16(b.z); u.h[7] = __float2bfloat16(b.w);
  *(bf16x8*)(d + mat * 262144 + i) = u.v;
}

// ---------------------------------------------------------------------------
// 256x256x(K=512) GEMM, 8 waves (2M x 4N), BK=64, 4 phases/K-tile with
// fragment reuse, DEEP staging pipeline:
//   P1: read A0,B0 -> TL
//   P2: read B1    -> TR ; stage A0(kt+2), B0(kt+2)   [same-parity buffer]
//   P3: read A1    -> BR ; stage B1(kt+2)
//   P4: (regs)     -> BL ; stage A1(kt+2) ; vmcnt(8)  [once per K-tile]
// Each stage lands >= 6 phases before consumption (>= HBM latency); each
// overwrite is >= 1 barrier after that half's last LDS read (WAR-safe).
// vmcnt(8) leaves exactly this K-tile's 8 loads outstanding -> all older
// staged data (incl. K-tile kt+1, staged during kt-1) is landed+published.
// T5 setprio, T1 XCD swizzle, XOR-swizzled LDS (both-sides).
// MODE 0: fp32 direct store.  MODE 1/2: bf16 QKV store [a][h][seq][e] via
// LDS-staged coalesced epilogue (m-decode per stage).
// ---------------------------------------------------------------------------
template<int MODE, int NBN>
__global__ __launch_bounds__(512)
void gemm2_k(const bf16* __restrict__ A,
             const bf16* __restrict__ W0, const bf16* __restrict__ W1, const bf16* __restrict__ W2,
             const float* __restrict__ Bi0, const float* __restrict__ Bi1, const float* __restrict__ Bi2,
             bf16* __restrict__ O0, bf16* __restrict__ O1, bf16* __restrict__ O2,
             float* __restrict__ F0)
{
  // 2 K-tile buffers x { A halves @0/16384, B halves @32768/49152 } = 128 KB
  __shared__ __align__(16) char smem[131072];

  const int tid  = threadIdx.x;
  const int lane = tid & 63;
  const int wid  = tid >> 6;        // 0..7
  const int wm   = wid >> 2;        // 0..1
  const int wn   = wid & 3;         // 0..3
  const int lq   = lane & 15, qd = lane >> 4;

  // T1: XCD-contiguous stripes (grid % 8 == 0)
  const int per = gridDim.x >> 3;
  const int logical = (blockIdx.x & 7) * per + (blockIdx.x >> 3);
  const int bm = logical / NBN;
  const int bn = logical % NBN;
  const int m0 = bm * 256;
  const int n0 = bn * 256;

  const bf16* Wb; const float* Bsel; int nbase;
  if (MODE == 0) { Wb = W0; Bsel = Bi0; nbase = n0; }
  else {
    const int mat = n0 >> 9; nbase = n0 & 511;
    Wb   = (mat == 0) ? W0 : ((mat == 1) ? W1 : W2);
    Bsel = (mat == 0) ? Bi0 : ((mat == 1) ? Bi1 : Bi2);
  }

  f32x4 acc[8][4];
#pragma unroll
  for (int i = 0; i < 8; ++i)
#pragma unroll
    for (int j = 0; j < 4; ++j) acc[i][j] = f32x4{0.f, 0.f, 0.f, 0.f};

  // stage one half-tile (X: 0=A tokens, 1=B weights; h: 0/1; K-tile ktt; buffer tb)
  auto stage_half = [&](int X, int h, int ktt, int tb) {
#pragma unroll
    for (int jj = 0; jj < 2; ++jj) {
      const int id = wid * 2 + jj;                  // 0..15
      const int r  = id * 8 + (lane >> 3);          // row in half 0..127
      const int cb = ktt * 128 + (((lane & 7) ^ (r & 7)) << 4);  // pre-swizzled
      const char* g = X ? (const char*)Wb + (size_t)(nbase + h * 128 + r) * 1024 + cb
                        : (const char*)A  + (size_t)(m0   + h * 128 + r) * 1024 + cb;
      gload_lds16(g, smem + tb * 65536 + X * 32768 + h * 16384 + id * 1024);
    }
  };

  auto lda = [&](bf16x8 (&af)[4][2], const char* Ah) {
#pragma unroll
    for (int i = 0; i < 4; ++i) {
      const int row = wm * 64 + i * 16 + lq;
#pragma unroll
      for (int kk = 0; kk < 2; ++kk)
        af[i][kk] = *(const bf16x8*)(Ah + row * 128 + (((kk * 4 + qd) ^ (row & 7)) << 4));
    }
  };
  auto ldb = [&](bf16x8 (&bv)[2][2], const char* Bh) {
#pragma unroll
    for (int j = 0; j < 2; ++j) {
      const int row = wn * 32 + j * 16 + lq;
#pragma unroll
      for (int kk = 0; kk < 2; ++kk)
        bv[j][kk] = *(const bf16x8*)(Bh + row * 128 + (((kk * 4 + qd) ^ (row & 7)) << 4));
    }
  };

#define FMA_Q(AF, BV, QM, QN) do {                                               \
    __builtin_amdgcn_s_setprio(1);                                              \
    _Pragma("unroll") for (int kk = 0; kk < 2; ++kk)                             \
      _Pragma("unroll") for (int i = 0; i < 4; ++i)                              \
        _Pragma("unroll") for (int j = 0; j < 2; ++j)                            \
          acc[(QM) * 4 + i][(QN) * 2 + j] =                                      \
              mfma16(AF[i][kk], BV[j][kk], acc[(QM) * 4 + i][(QN) * 2 + j]);     \
    __builtin_amdgcn_s_setprio(0);                                               \
  } while (0)

#define PHASE_BAR() do {                                                         \
    __builtin_amdgcn_s_barrier();                                                \
    __builtin_amdgcn_sched_barrier(0);                                           \
  } while (0)

#define KTILE_END() do {                                                         \
    asm volatile("s_waitcnt vmcnt(8)" ::: "memory");                             \
    __builtin_amdgcn_s_barrier();                                                \
    __builtin_amdgcn_sched_barrier(0);                                           \
  } while (0)

  // prologue: fully stage kt0 (buf0) and kt1 (buf1); drain kt0's 8 loads
  stage_half(0, 0, 0, 0); stage_half(1, 0, 0, 0);
  stage_half(1, 1, 0, 0); stage_half(0, 1, 0, 0);
  stage_half(0, 0, 1, 1); stage_half(1, 0, 1, 1);
  stage_half(1, 1, 1, 1); stage_half(0, 1, 1, 1);
  KTILE_END();

  bf16x8 afA[4][2], afB[4][2], bv0[2][2], bv1[2][2];

  for (int kt = 0; kt < 8; ++kt) {     // K = 512, BK = 64
    const int bb = (kt & 1) * 65536;
    const int k2 = (kt + 2) & 7;       // wrapped tail dummies keep ledger uniform
    const int tb = kt & 1;             // (kt+2) parity == kt parity
    // P1: TL = A0 x B0
    lda(afA, smem + bb);
    ldb(bv0, smem + bb + 32768);
    FMA_Q(afA, bv0, 0, 0);
    PHASE_BAR();
    // P2: TR = A0 x B1 ; stage A0(kt+2), B0(kt+2)
    ldb(bv1, smem + bb + 32768 + 16384);
    stage_half(0, 0, k2, tb);
    stage_half(1, 0, k2, tb);
    FMA_Q(afA, bv1, 0, 1);
    PHASE_BAR();
    // P3: BR = A1 x B1 ; stage B1(kt+2)
    lda(afB, smem + bb + 16384);
    stage_half(1, 1, k2, tb);
    FMA_Q(afB, bv1, 1, 1);
    PHASE_BAR();
    // P4: BL = A1 x B0 ; stage A1(kt+2) ; single counted drain per K-tile
    stage_half(0, 1, k2, tb);
    FMA_Q(afB, bv0, 1, 0);
    KTILE_END();
  }
#undef FMA_Q
#undef PHASE_BAR
#undef KTILE_END

  // drain all outstanding stage writes before reusing LDS / exiting
  asm volatile("s_waitcnt vmcnt(0)" ::: "memory");
  __builtin_amdgcn_s_barrier();
  __builtin_amdgcn_sched_barrier(0);

  float biasv[4];
#pragma unroll
  for (int ni = 0; ni < 4; ++ni) {
    const int col = (ni >> 1) * 128 + wn * 32 + (ni & 1) * 16 + lq;
    biasv[ni] = Bsel[(MODE == 0) ? (n0 + col) : (nbase + col)];
  }

  if (MODE == 0) {
#pragma unroll
    for (int mi = 0; mi < 8; ++mi)
#pragma unroll
      for (int r = 0; r < 4; ++r) {
        const int m = m0 + (mi >> 2) * 128 + wm * 64 + (mi & 3) * 16 + qd * 4 + r;
#pragma unroll
        for (int ni = 0; ni < 4; ++ni) {
          const int n = n0 + (ni >> 1) * 128 + wn * 32 + (ni & 1) * 16 + lq;
          F0[(size_t)m * 512 + n] = acc[mi][ni][r] + biasv[ni];
        }
      }
  } else {
    // two passes (qm = m-half); Ct logical [128][256] bf16, slot-swizzled
    const int mat = n0 >> 9;
    bf16* const Om = (mat == 0) ? O0 : ((mat == 1) ? O1 : O2);
    const int h0 = (n0 & 511) >> 6;          // first head of this 256-col chunk
#pragma unroll
    for (int qm = 0; qm < 2; ++qm) {
#pragma unroll
      for (int i = 0; i < 4; ++i)
#pragma unroll
        for (int r = 0; r < 4; ++r) {
          const int row = wm * 64 + i * 16 + qd * 4 + r;         // 0..127
          const int sw  = (row & 7) ^ (((row >> 3) & 3) << 3);
#pragma unroll
          for (int ni = 0; ni < 4; ++ni) {
            const int col  = (ni >> 1) * 128 + wn * 32 + (ni & 1) * 16 + lq;
            const int byte = row * 512 + (((col >> 3) ^ sw) << 4) + (col & 7) * 2;
            *(bf16*)(smem + byte) = __float2bfloat16(acc[qm * 4 + i][ni][r] + biasv[ni]);
          }
        }
      __syncthreads();
      {
        const int hh   = tid >> 7;           // 0..3
        const int mrow = tid & 127;
        const int m    = m0 + qm * 128 + mrow;
        int a, seq;
        if (MODE == 1) {
          const int b = m >> 13, c = (m >> 3) & 1023, pp = m & 7;
          a = (b * 32 + (c >> 5)) * 8 + pp;  seq = c & 31;
        } else {
          a = m >> 5;  seq = m & 31;
        }
        const int sw = (mrow & 7) ^ (((mrow >> 3) & 3) << 3);
        bf16* const dst = Om + ((size_t)((a * 8 + h0 + hh) * 32 + seq)) * 64;
#pragma unroll
        for (int j = 0; j < 8; ++j) {
          const bf16x8 v = *(const bf16x8*)(smem + mrow * 512 + (((hh * 8 + j) ^ sw) << 4));
          *(bf16x8*)(dst + j * 8) = v;
        }
      }
      __syncthreads();
    }
  }
}

// ---------------------------------------------------------------------------
// Attention: one wave = one (a,h) task. L=32, E=64. (proven round-5 kernel)
// ---------------------------------------------------------------------------
template<int STAGE>
__global__ __launch_bounds__(256)
void attn_k(const bf16* __restrict__ Q, const bf16* __restrict__ K,
            const bf16* __restrict__ V, bf16* __restrict__ Y)
{
  __shared__ __align__(16) char Plds[4][32 * 80];
  __shared__ __align__(16) char Vlds[4][32 * 132];
  const int tid  = threadIdx.x;
  const int lane = tid & 63;
  const int w    = tid >> 6;
  const int task = blockIdx.x * 4 + w;
  const int a = task >> 3, h = task & 7;
  const int lq = lane & 15, qd = lane >> 4;

  const bf16* Qb = Q + (size_t)(a * 8 + h) * 2048;
  const bf16* Kb = K + (size_t)(a * 8 + h) * 2048;
  const bf16* Vb = V + (size_t)(a * 8 + h) * 2048;

  {
    const int r  = lane >> 1;
    const int c0 = (lane & 1) * 32;
    union { bf16x8 v; unsigned u[4]; } t0, t1, t2, t3;
    t0.v = *(const bf16x8*)(Vb + r * 64 + c0);
    t1.v = *(const bf16x8*)(Vb + r * 64 + c0 + 8);
    t2.v = *(const bf16x8*)(Vb + r * 64 + c0 + 16);
    t3.v = *(const bf16x8*)(Vb + r * 64 + c0 + 24);
    unsigned* dst = (unsigned*)(Vlds[w] + r * 132 + c0 * 2);
#pragma unroll
    for (int j = 0; j < 4; ++j) dst[j]      = t0.u[j];
#pragma unroll
    for (int j = 0; j < 4; ++j) dst[4 + j]  = t1.u[j];
#pragma unroll
    for (int j = 0; j < 4; ++j) dst[8 + j]  = t2.u[j];
#pragma unroll
    for (int j = 0; j < 4; ++j) dst[12 + j] = t3.u[j];
  }

  bf16x8 qf[2][2], kf[2][2];
#pragma unroll
  for (int mi = 0; mi < 2; ++mi)
#pragma unroll
    for (int ks = 0; ks < 2; ++ks) {
      qf[mi][ks] = *(const bf16x8*)(Qb + (mi * 16 + lq) * 64 + ks * 32 + qd * 8);
      kf[mi][ks] = *(const bf16x8*)(Kb + (mi * 16 + lq) * 64 + ks * 32 + qd * 8);
    }

  f32x4 s[2][2];
#pragma unroll
  for (int mi = 0; mi < 2; ++mi)
#pragma unroll
    for (int ni = 0; ni < 2; ++ni) {
      s[mi][ni] = f32x4{0.f, 0.f, 0.f, 0.f};
#pragma unroll
      for (int ks = 0; ks < 2; ++ks)
        s[mi][ni] = mfma16(qf[mi][ks], kf[ni][ks], s[mi][ni]);
    }

  char* Pw = Plds[w];
  float rden[2][4];
#pragma unroll
  for (int mi = 0; mi < 2; ++mi) {
#pragma unroll
    for (int r = 0; r < 4; ++r) {
      float v0 = s[mi][0][r] * 0.125f, v1 = s[mi][1][r] * 0.125f;
      float mx = fmaxf(v0, v1);
#pragma unroll
      for (int d = 1; d < 16; d <<= 1) mx = fmaxf(mx, __shfl_xor(mx, d, 64));
      const float p0 = __expf(v0 - mx), p1 = __expf(v1 - mx);
      float sm = p0 + p1;
#pragma unroll
      for (int d = 1; d < 16; d <<= 1) sm += __shfl_xor(sm, d, 64);
      rden[mi][r] = 1.f / sm;
      const int qrow = mi * 16 + qd * 4 + r;
      bf16* prow = (bf16*)(Pw + qrow * 80);
      prow[lq]      = __float2bfloat16(p0);
      prow[16 + lq] = __float2bfloat16(p1);
    }
  }
  asm volatile("s_waitcnt lgkmcnt(0)" ::: "memory");
  __builtin_amdgcn_sched_barrier(0);

  bf16x8 pf[2];
#pragma unroll
  for (int mi = 0; mi < 2; ++mi)
    pf[mi] = *(const bf16x8*)(Pw + (mi * 16 + lq) * 80 + qd * 16);

  bf16x8 vf[4];
#pragma unroll
  for (int ni = 0; ni < 4; ++ni) {
    union { bf16 h[8]; bf16x8 v; } uv;
#pragma unroll
    for (int j = 0; j < 8; ++j)
      uv.h[j] = *(const bf16*)(Vlds[w] + (qd * 8 + j) * 132 + (ni * 16 + lq) * 2);
    vf[ni] = uv.v;
  }

  f32x4 o[2][4];
#pragma unroll
  for (int mi = 0; mi < 2; ++mi)
#pragma unroll
    for (int ni = 0; ni < 4; ++ni) {
      o[mi][ni] = f32x4{0.f, 0.f, 0.f, 0.f};
      o[mi][ni] = mfma16(pf[mi], vf[ni], o[mi][ni]);
    }

  int rowbase;
  if (STAGE == 1) { const int p = a & 7, ng = (a >> 3) & 31, b = a >> 8; rowbase = b * 8192 + p * 32 + ng; }
  else            { const int p = a & 7, i  = (a >> 3) & 31, b = a >> 8; rowbase = b * 8192 + i * 8 + p; }

#pragma unroll
  for (int mi = 0; mi < 2; ++mi) {
#pragma unroll
    for (int r = 0; r < 4; ++r) {
      const int q   = mi * 16 + qd * 4 + r;
      const int row = rowbase + q * 256;
      const float rd = rden[mi][r];
#pragma unroll
      for (int ni = 0; ni < 4; ++ni) {
        const int e = ni * 16 + lq;
        Y[(size_t)row * 512 + h * 64 + e] = __float2bfloat16(o[mi][ni][r] * rd);
      }
    }
  }
}

// ---------------------------------------------------------------------------
extern "C" void kernel_launch(void* const* d_in, const int* in_sizes, int n_in,
                              void* d_out, int out_size, void* d_ws, size_t ws_size,
                              hipStream_t stream) {
  const float* x   = (const float*)d_in[0];
  const float* q1w = (const float*)d_in[1];
  const float* q1b = (const float*)d_in[2];
  const float* k1w = (const float*)d_in[3];
  const float* k1b = (const float*)d_in[4];
  const float* v1w = (const float*)d_in[5];
  const float* v1b = (const float*)d_in[6];
  const float* q2w = (const float*)d_in[7];
  const float* q2b = (const float*)d_in[8];
  const float* k2w = (const float*)d_in[9];
  const float* k2b = (const float*)d_in[10];
  const float* v2w = (const float*)d_in[11];
  const float* v2b = (const float*)d_in[12];
  const float* ow  = (const float*)d_in[13];
  const float* ob  = (const float*)d_in[14];
  float* out = (float*)d_out;

  const size_t TOK = 65536ull * 512ull;
  const size_t WS1 = 262144;
  bf16* Xbf = (bf16*)d_ws;
  bf16* Qb  = Xbf + TOK;
  bf16* Kb  = Qb + TOK;
  bf16* Vb  = Kb + TOK;
  bf16* Wbf = Vb + TOK;   // 7 x 512x512 (q1,k1,v1,q2,k2,v2,ow)
  bf16* X2  = Xbf;

  cvt_x_k<<<16384, 256, 0, stream>>>(x, Xbf);
  cvt_w_k<<<7 * 128, 256, 0, stream>>>(q1w, k1w, v1w, q2w, k2w, v2w, ow, Wbf);

  gemm2_k<1, 6><<<1536, 512, 0, stream>>>(Xbf, Wbf, Wbf + WS1, Wbf + 2 * WS1,
                                          q1b, k1b, v1b, Qb, Kb, Vb, nullptr);
  attn_k<1><<<4096, 256, 0, stream>>>(Qb, Kb, Vb, X2);
  gemm2_k<2, 6><<<1536, 512, 0, stream>>>(X2, Wbf + 3 * WS1, Wbf + 4 * WS1, Wbf + 5 * WS1,
                                          q2b, k2b, v2b, Qb, Kb, Vb, nullptr);
  attn_k<2><<<4096, 256, 0, stream>>>(Qb, Kb, Vb, X2);
  gemm2_k<0, 2><<<512, 512, 0, stream>>>(X2, Wbf + 6 * WS1, Wbf + 6 * WS1, Wbf + 6 * WS1,
                                         ob, ob, ob, nullptr, nullptr, nullptr, out);
}